// Round 1
// baseline (286.121 us; speedup 1.0000x reference)
//
#include <hip/hip_runtime.h>

#define T_TOK 8192
#define D_IN  4096
#define D_OUT 4096

typedef _Float16 h2 __attribute__((ext_vector_type(2)));
typedef _Float16 h4 __attribute__((ext_vector_type(4)));
typedef _Float16 h8 __attribute__((ext_vector_type(8)));
typedef float    f4v __attribute__((ext_vector_type(4)));

__device__ __forceinline__ h2 pkrtz(float a, float b) {
    auto r = __builtin_amdgcn_cvt_pkrtz(a, b);
    h2 o; __builtin_memcpy(&o, &r, 4); return o;
}
__device__ __forceinline__ h8 cvt8(float4 f0, float4 f1) {
    h2 p0 = pkrtz(f0.x, f0.y), p1 = pkrtz(f0.z, f0.w);
    h2 p2 = pkrtz(f1.x, f1.y), p3 = pkrtz(f1.z, f1.w);
    return (h8){p0.x, p0.y, p1.x, p1.y, p2.x, p2.y, p3.x, p3.y};
}
__device__ __forceinline__ h8 as_h8(uint4 u) { h8 b; __builtin_memcpy(&b, &u, 16); return b; }

// MFMA 16x16x32 f16 layouts (verified m89/m91/m120):
//   A-frag: lane holds A[m=lane&15][k=(lane>>4)*8+j], j=0..7 (one 16B h8)
//   B-frag: lane holds B[k=(lane>>4)*8+j][n=lane&15]
//   C/D:    row=(lane>>4)*4+reg, col=lane&15
// Fragment-chunk layout for a KxN panel: off = ((k>>3)*N + n)*8 + (k&7)

// ---- prep: Wa->WaB frags (bid<256), Wb->WbB frags (bid<384), aux_partial ----
__global__ __launch_bounds__(256)
void prep(const float* __restrict__ Wa, const float* __restrict__ Wb,
          const float* __restrict__ la, const float* __restrict__ lb,
          _Float16* __restrict__ WaB, _Float16* __restrict__ WbB,
          double* __restrict__ pax) {
    const int bid = blockIdx.x, tx = threadIdx.x;
    __shared__ double red[4][16];
    if (bid < 256) {
        // Wa [er=64][k=4096] f32 -> frag order ((k>>3)*64+er)*8+(k&7)
        int gid = bid * 256 + tx;                // 0..65535
        int er = gid >> 10, k0 = (gid & 1023) * 4;
        float4 v = ((const float4*)Wa)[gid];
        h2 p0 = pkrtz(v.x, v.y), p1 = pkrtz(v.z, v.w);
        h4 o = { p0.x, p0.y, p1.x, p1.y };
        *(h4*)(WaB + ((k0 >> 3) * 64 + er) * 8 + (k0 & 7)) = o;
    } else if (bid < 384) {
        // Wb [e][o][r] f32 -> frag order ((er>>3)*4096+o)*8+(er&7), er=e*8+r
        // thread per (e,o): read 8 contiguous f32, write contiguous h8
        int gid = (bid - 256) * 256 + tx;        // 0..32767
        int e = gid >> 12, o = gid & 4095;
        const float4* p = (const float4*)(Wb + ((size_t)e * 4096 + o) * 8);
        h8 v = cvt8(p[0], p[1]);
        *(h8*)(WbB + ((size_t)e * 4096 + o) * 8) = v;
    } else {
        // aux_partial: 32 blocks, per-token full softmax partial sums (f64)
        const int ab = bid - 384;
        const int t = ab * 256 + tx;
        double loc[16];
        {
            float l[8];
#pragma unroll
            for (int i = 0; i < 8; ++i) l[i] = la[(size_t)t * 8 + i];
            float m = l[0];
#pragma unroll
            for (int i = 1; i < 8; ++i) m = fmaxf(m, l[i]);
            float s = 0.f, e[8];
#pragma unroll
            for (int i = 0; i < 8; ++i) { e[i] = __expf(l[i] - m); s += e[i]; }
#pragma unroll
            for (int i = 0; i < 8; ++i) loc[i] = (double)(e[i] / s);
        }
        {
            float l[8];
#pragma unroll
            for (int i = 0; i < 8; ++i) l[i] = lb[(size_t)t * 8 + i];
            float m = l[0];
#pragma unroll
            for (int i = 1; i < 8; ++i) m = fmaxf(m, l[i]);
            float s = 0.f, e[8];
#pragma unroll
            for (int i = 0; i < 8; ++i) { e[i] = __expf(l[i] - m); s += e[i]; }
#pragma unroll
            for (int i = 0; i < 8; ++i) loc[8 + i] = (double)(e[i] / s);
        }
        const int lane = tx & 63, wid = tx >> 6;
#pragma unroll
        for (int v = 0; v < 16; ++v) {
            double s = loc[v];
#pragma unroll
            for (int off = 32; off > 0; off >>= 1) s += __shfl_down(s, off, 64);
            if (lane == 0) red[wid][v] = s;
        }
        __syncthreads();
        if (tx < 16)
            pax[ab * 16 + tx] = red[0][tx] + red[1][tx] + red[2][tx] + red[3][tx];
    }
}

// ---- fused: GEMM1 (x@WaT) + routing + GEMM2 (Mb@WbF) in one pass ------------
// 512 blocks x 256 thr; 16 tokens/block; 4 waves = 4 er-groups (G1) / 4 col-groups (G2)
__global__ __launch_bounds__(256)
void fused(const float* __restrict__ x, const _Float16* __restrict__ WaB,
           const _Float16* __restrict__ WbB, const float* __restrict__ la,
           const float* __restrict__ lb, float* __restrict__ out,
           const double* __restrict__ pax) {
    __shared__ float    pL[16][66];      // part[t][er], padded
    __shared__ _Float16 MbL[1024];       // Mb frags: ((er>>3)*16+t)*8+(er&7)
    __shared__ float    sW0[16], sW1[16], sCb[16][8];
    __shared__ int      sE0[16], sE1[16];
    __shared__ double   sl[16];

    const int tx = threadIdx.x, l = tx & 63, w = tx >> 6;
    const int mr = l & 15, kf = l >> 4;
    const int m0 = blockIdx.x * 16;
    const int er1 = w * 16 + mr;

    // ================= phase 1: part[16x64] = x[16x4096] @ WaT ===============
    // Barrier-free: A-frags loaded per-lane direct from x + pkrtz in-register;
    // B-frags direct from fragment-ordered WaB. Depth-1 ping-pong pipeline.
    f4v acc = (f4v){0.f, 0.f, 0.f, 0.f};
    const float* xr = x + (size_t)(m0 + mr) * D_IN + kf * 8;
    const uint4* wa4 = (const uint4*)WaB;

    float4 A0[8], A1[8]; uint4 B0[4], B1[4];

#define LD1(Ad, Bd, IT) do {                                                   \
    const float* ap_ = xr + (IT) * 128;                                        \
    _Pragma("unroll") for (int ks_ = 0; ks_ < 4; ++ks_) {                      \
        Ad[2 * ks_]     = *(const float4*)(ap_ + ks_ * 32);                    \
        Ad[2 * ks_ + 1] = *(const float4*)(ap_ + ks_ * 32 + 4); }              \
    _Pragma("unroll") for (int ks_ = 0; ks_ < 4; ++ks_)                        \
        Bd[ks_] = wa4[(size_t)(((IT) * 16 + ks_ * 4 + kf) * 64) + er1];        \
  } while (0)

#define CMP1(As, Bs) do {                                                      \
    _Pragma("unroll") for (int ks_ = 0; ks_ < 4; ++ks_) {                      \
        h8 a_ = cvt8(As[2 * ks_], As[2 * ks_ + 1]);                            \
        acc = __builtin_amdgcn_mfma_f32_16x16x32_f16(a_, as_h8(Bs[ks_]), acc,  \
                                                     0, 0, 0); }               \
  } while (0)

    LD1(A0, B0, 0);
#pragma unroll 1
    for (int it = 0; it < 30; it += 2) {
        LD1(A1, B1, it + 1); CMP1(A0, B0);
        LD1(A0, B0, it + 2); CMP1(A1, B1);
    }
    LD1(A1, B1, 31); CMP1(A0, B0); CMP1(A1, B1);
#undef LD1
#undef CMP1

    // ================= phase 2: routing -> Mb fragment panel =================
#pragma unroll
    for (int r = 0; r < 4; ++r) pL[kf * 4 + r][er1] = acc[r];
    __syncthreads();

    if (tx < 16) {
        const int t = tx;
        float lg[8];
#pragma unroll
        for (int i = 0; i < 8; ++i) lg[i] = la[(size_t)(m0 + t) * 8 + i];
        int e0 = 0; float b0 = lg[0];
#pragma unroll
        for (int i = 1; i < 8; ++i) if (lg[i] > b0) { b0 = lg[i]; e0 = i; }
        int e1 = -1; float b1 = -1e30f;
#pragma unroll
        for (int i = 0; i < 8; ++i) if (i != e0 && lg[i] > b1) { b1 = lg[i]; e1 = i; }
        float w1 = __expf(b1 - b0), s = 1.f + w1;
        sW0[t] = 1.f / s; sW1[t] = w1 / s; sE0[t] = e0; sE1[t] = e1;

#pragma unroll
        for (int i = 0; i < 8; ++i) lg[i] = lb[(size_t)(m0 + t) * 8 + i];
        int f0 = 0; float c0 = lg[0];
#pragma unroll
        for (int i = 1; i < 8; ++i) if (lg[i] > c0) { c0 = lg[i]; f0 = i; }
        int f1 = -1; float c1 = -1e30f;
#pragma unroll
        for (int i = 0; i < 8; ++i) if (i != f0 && lg[i] > c1) { c1 = lg[i]; f1 = i; }
        float wb1 = __expf(c1 - c0), sb = 1.f + wb1;
        float wb0s = 2.f / sb, wb1s = 2.f * wb1 / sb;   // SCALING=2 folded in
#pragma unroll
        for (int e = 0; e < 8; ++e)
            sCb[t][e] = (e == f0) ? wb0s : (e == f1) ? wb1s : 0.f;
    }
    __syncthreads();

    {
        const int t = tx >> 4, g = tx & 15;
        const float w0 = sW0[t], w1 = sW1[t];
        const int e0 = sE0[t], e1 = sE1[t];
        const float cb = sCb[t][g >> 1];
        h4 o;
#pragma unroll
        for (int j = 0; j < 4; ++j) {
            int r = (g * 4 + j) & 7;
            float mid = w0 * pL[t][e0 * 8 + r] + w1 * pL[t][e1 * 8 + r];
            o[j] = (_Float16)(cb * mid);
        }
        *(h4*)(MbL + ((g >> 1) * 16 + t) * 8 + (g & 1) * 4) = o;
    }
    __syncthreads();

    // ================= phase 3: out[16x4096] = Mb[16x64] @ WbF ===============
    // A-frags in regs (loaded once); B-frags per-wave direct from L2-resident
    // fragment-ordered WbB; stores straight to out. Barrier-free, depth-1 pipe.
    h8 a30, a31;
    a30 = *(const h8*)(MbL + ((0 * 4 + kf) * 16 + mr) * 8);
    a31 = *(const h8*)(MbL + ((1 * 4 + kf) * 16 + mr) * 8);
    const uint4* wb4 = (const uint4*)WbB;
    const size_t bofs0 = (size_t)((0 * 4 + kf) * 4096);
    const size_t bofs1 = (size_t)((1 * 4 + kf) * 4096);
    float* outp = out + (size_t)(m0 + kf * 4) * D_OUT;

    uint4 C0[4], C1[4];
#define LDB3(Cd, CH) do { int n0_ = (CH) * 128 + w * 32 + mr;                  \
    Cd[0] = wb4[bofs0 + n0_];      Cd[1] = wb4[bofs0 + n0_ + 16];              \
    Cd[2] = wb4[bofs1 + n0_];      Cd[3] = wb4[bofs1 + n0_ + 16];              \
  } while (0)

#define CMP3(Cs, CH) do {                                                      \
    f4v o0 = (f4v){0.f,0.f,0.f,0.f}, o1 = (f4v){0.f,0.f,0.f,0.f};              \
    o0 = __builtin_amdgcn_mfma_f32_16x16x32_f16(a30, as_h8(Cs[0]), o0, 0,0,0); \
    o0 = __builtin_amdgcn_mfma_f32_16x16x32_f16(a31, as_h8(Cs[2]), o0, 0,0,0); \
    o1 = __builtin_amdgcn_mfma_f32_16x16x32_f16(a30, as_h8(Cs[1]), o1, 0,0,0); \
    o1 = __builtin_amdgcn_mfma_f32_16x16x32_f16(a31, as_h8(Cs[3]), o1, 0,0,0); \
    int n0_ = (CH) * 128 + w * 32 + mr;                                        \
    _Pragma("unroll") for (int r_ = 0; r_ < 4; ++r_) {                         \
        outp[(size_t)r_ * D_OUT + n0_]      = o0[r_];                          \
        outp[(size_t)r_ * D_OUT + n0_ + 16] = o1[r_]; }                        \
  } while (0)

    LDB3(C0, 0);
#pragma unroll 1
    for (int c = 0; c < 30; c += 2) {
        LDB3(C1, c + 1); CMP3(C0, c);
        LDB3(C0, c + 2); CMP3(C1, c + 1);
    }
    LDB3(C1, 31); CMP3(C0, 30); CMP3(C1, 31);
#undef LDB3
#undef CMP3

    // ================= aux_final (block 0 only) ==============================
    if (blockIdx.x == 0) {
        if (tx < 16) {
            double s = 0.0;
#pragma unroll
            for (int b = 0; b < 32; ++b) s += pax[b * 16 + tx];
            sl[tx] = s;
        }
        __syncthreads();
        if (tx == 0) {
            double pa[8], pb[8], ma = 0.0, mb = 0.0;
            for (int e = 0; e < 8; ++e) { pa[e] = sl[e] / 8192.0;     ma += pa[e] / 8.0; }
            for (int e = 0; e < 8; ++e) { pb[e] = sl[8 + e] / 8192.0; mb += pb[e] / 8.0; }
            double va = 0.0, vb = 0.0;
            for (int e = 0; e < 8; ++e) { double d = pa[e] - ma; va += d * d; }
            for (int e = 0; e < 8; ++e) { double d = pb[e] - mb; vb += d * d; }
            out[(size_t)T_TOK * D_OUT + 0] = (float)(8.0 * va / 7.0);
            out[(size_t)T_TOK * D_OUT + 1] = (float)(8.0 * vb / 7.0);
        }
    }
}

extern "C" void kernel_launch(void* const* d_in, const int* in_sizes, int n_in,
                              void* d_out, int out_size, void* d_ws, size_t ws_size,
                              hipStream_t stream) {
    const float* x  = (const float*)d_in[0];
    const float* la = (const float*)d_in[1];
    const float* lb = (const float*)d_in[2];
    const float* Wa = (const float*)d_in[3];
    const float* Wb = (const float*)d_in[4];
    float* out = (float*)d_out;

    char* ws = (char*)d_ws;
    _Float16* WaB = (_Float16*)ws;                 // 512 KB
    _Float16* WbB = (_Float16*)(ws + 524288);      // 512 KB
    double*   pax = (double*)(ws + 1048576);       // 4 KB

    prep<<<416, 256, 0, stream>>>(Wa, Wb, la, lb, WaB, WbB, pax);
    fused<<<512, 256, 0, stream>>>(x, WaB, WbB, la, lb, out, pax);
}

// Round 2
// 284.313 us; speedup vs baseline: 1.0064x; 1.0064x over previous
//
#include <hip/hip_runtime.h>

#define T_TOK 8192
#define D_IN  4096
#define D_OUT 4096

typedef _Float16 h2 __attribute__((ext_vector_type(2)));
typedef _Float16 h4 __attribute__((ext_vector_type(4)));
typedef _Float16 h8 __attribute__((ext_vector_type(8)));
typedef float    f4v __attribute__((ext_vector_type(4)));

__device__ __forceinline__ h2 pkrtz(float a, float b) {
    auto r = __builtin_amdgcn_cvt_pkrtz(a, b);
    h2 o; __builtin_memcpy(&o, &r, 4); return o;
}
__device__ __forceinline__ h8 cvt8(float4 f0, float4 f1) {
    h2 p0 = pkrtz(f0.x, f0.y), p1 = pkrtz(f0.z, f0.w);
    h2 p2 = pkrtz(f1.x, f1.y), p3 = pkrtz(f1.z, f1.w);
    return (h8){p0.x, p0.y, p1.x, p1.y, p2.x, p2.y, p3.x, p3.y};
}
__device__ __forceinline__ h8 as_h8(uint4 u) { h8 b; __builtin_memcpy(&b, &u, 16); return b; }

// MFMA 16x16x32 f16 layouts (verified m89/m91/m120):
//   A-frag: lane holds A[m=lane&15][k=(lane>>4)*8+j], j=0..7 (one 16B h8)
//   B-frag: lane holds B[k=(lane>>4)*8+j][n=lane&15]
//   C/D:    row=(lane>>4)*4+reg, col=lane&15
// Fragment-chunk layout for a KxN panel: off = ((k>>3)*N + n)*8 + (k&7)

// ---- prep: Wa->WaB frags (bid<256), Wb->WbB frags (bid<384), aux_partial ----
__global__ __launch_bounds__(256)
void prep(const float* __restrict__ Wa, const float* __restrict__ Wb,
          const float* __restrict__ la, const float* __restrict__ lb,
          _Float16* __restrict__ WaB, _Float16* __restrict__ WbB,
          double* __restrict__ pax) {
    const int bid = blockIdx.x, tx = threadIdx.x;
    __shared__ double red[4][16];
    if (bid < 256) {
        // Wa [er=64][k=4096] f32 -> frag order ((k>>3)*64+er)*8+(k&7)
        int gid = bid * 256 + tx;                // 0..65535
        int er = gid >> 10, k0 = (gid & 1023) * 4;
        float4 v = ((const float4*)Wa)[gid];
        h2 p0 = pkrtz(v.x, v.y), p1 = pkrtz(v.z, v.w);
        h4 o = { p0.x, p0.y, p1.x, p1.y };
        *(h4*)(WaB + ((k0 >> 3) * 64 + er) * 8 + (k0 & 7)) = o;
    } else if (bid < 384) {
        // Wb [e][o][r] f32 -> frag order ((er>>3)*4096+o)*8+(er&7), er=e*8+r
        int gid = (bid - 256) * 256 + tx;        // 0..32767
        int e = gid >> 12, o = gid & 4095;
        const float4* p = (const float4*)(Wb + ((size_t)e * 4096 + o) * 8);
        h8 v = cvt8(p[0], p[1]);
        *(h8*)(WbB + ((size_t)e * 4096 + o) * 8) = v;
    } else {
        // aux_partial: 32 blocks, per-token full softmax partial sums (f64)
        const int ab = bid - 384;
        const int t = ab * 256 + tx;
        double loc[16];
        {
            float l[8];
#pragma unroll
            for (int i = 0; i < 8; ++i) l[i] = la[(size_t)t * 8 + i];
            float m = l[0];
#pragma unroll
            for (int i = 1; i < 8; ++i) m = fmaxf(m, l[i]);
            float s = 0.f, e[8];
#pragma unroll
            for (int i = 0; i < 8; ++i) { e[i] = __expf(l[i] - m); s += e[i]; }
#pragma unroll
            for (int i = 0; i < 8; ++i) loc[i] = (double)(e[i] / s);
        }
        {
            float l[8];
#pragma unroll
            for (int i = 0; i < 8; ++i) l[i] = lb[(size_t)t * 8 + i];
            float m = l[0];
#pragma unroll
            for (int i = 1; i < 8; ++i) m = fmaxf(m, l[i]);
            float s = 0.f, e[8];
#pragma unroll
            for (int i = 0; i < 8; ++i) { e[i] = __expf(l[i] - m); s += e[i]; }
#pragma unroll
            for (int i = 0; i < 8; ++i) loc[8 + i] = (double)(e[i] / s);
        }
        const int lane = tx & 63, wid = tx >> 6;
#pragma unroll
        for (int v = 0; v < 16; ++v) {
            double s = loc[v];
#pragma unroll
            for (int off = 32; off > 0; off >>= 1) s += __shfl_down(s, off, 64);
            if (lane == 0) red[wid][v] = s;
        }
        __syncthreads();
        if (tx < 16)
            pax[ab * 16 + tx] = red[0][tx] + red[1][tx] + red[2][tx] + red[3][tx];
    }
}

// ---- fused: GEMM1 (x@WaT) + routing + GEMM2 (Mb@WbF) in one pass ------------
// 512 blocks x 512 thr (8 waves); 16 tokens/block.
// Phase 1: 8 waves = 4 er-groups x 2 K-halves (K-split raises waves/CU 8->16).
// Phase 3: 8 waves = 8 column-slices of the 4096-wide output.
__global__ __launch_bounds__(512, 4)
void fused(const float* __restrict__ x, const _Float16* __restrict__ WaB,
           const _Float16* __restrict__ WbB, const float* __restrict__ la,
           const float* __restrict__ lb, float* __restrict__ out,
           const double* __restrict__ pax) {
    __shared__ float    pL[2][16][66];   // part[kh][t][er], padded
    __shared__ _Float16 MbL[1024];       // Mb frags: ((er>>3)*16+t)*8+(er&7)
    __shared__ float    sW0[16], sW1[16], sCb[16][8];
    __shared__ int      sE0[16], sE1[16];
    __shared__ double   sl[16];

    const int tx = threadIdx.x, l = tx & 63, w = tx >> 6;
    const int mr = l & 15, kf = l >> 4;
    const int m0 = blockIdx.x * 16;
    const int g  = w & 3;          // er-group (phase 1)
    const int kh = w >> 2;         // K-half   (phase 1)
    const int er1 = g * 16 + mr;

    // ================= phase 1: part[16x64] = x[16x4096] @ WaT ===============
    // Barrier-free K-loop: A-frags per-lane direct from x + pkrtz in-register;
    // B-frags direct from fragment-ordered WaB. Depth-1 ping-pong pipeline.
    f4v acc = (f4v){0.f, 0.f, 0.f, 0.f};
    const float* xr = x + (size_t)(m0 + mr) * D_IN + kh * 2048 + kf * 8;
    const uint4* wa4 = (const uint4*)WaB;
    const int itb = kh * 16;       // global 128-k chunk base for this K-half

    float4 A0[8], A1[8]; uint4 B0[4], B1[4];

#define LD1(Ad, Bd, IT) do {                                                   \
    const float* ap_ = xr + (IT) * 128;                                        \
    _Pragma("unroll") for (int ks_ = 0; ks_ < 4; ++ks_) {                      \
        Ad[2 * ks_]     = *(const float4*)(ap_ + ks_ * 32);                    \
        Ad[2 * ks_ + 1] = *(const float4*)(ap_ + ks_ * 32 + 4); }              \
    _Pragma("unroll") for (int ks_ = 0; ks_ < 4; ++ks_)                        \
        Bd[ks_] = wa4[(size_t)((((itb + (IT)) * 16 + ks_ * 4 + kf) * 64) + er1)]; \
  } while (0)

#define CMP1(As, Bs) do {                                                      \
    _Pragma("unroll") for (int ks_ = 0; ks_ < 4; ++ks_) {                      \
        h8 a_ = cvt8(As[2 * ks_], As[2 * ks_ + 1]);                            \
        acc = __builtin_amdgcn_mfma_f32_16x16x32_f16(a_, as_h8(Bs[ks_]), acc,  \
                                                     0, 0, 0); }               \
  } while (0)

    LD1(A0, B0, 0);
#pragma unroll 1
    for (int it = 0; it < 14; it += 2) {
        LD1(A1, B1, it + 1); CMP1(A0, B0);
        LD1(A0, B0, it + 2); CMP1(A1, B1);
    }
    LD1(A1, B1, 15); CMP1(A0, B0); CMP1(A1, B1);
#undef LD1
#undef CMP1

    // ================= phase 2: routing -> Mb fragment panel =================
#pragma unroll
    for (int r = 0; r < 4; ++r) pL[kh][kf * 4 + r][er1] = acc[r];
    __syncthreads();

    if (tx < 16) {
        const int t = tx;
        float lg[8];
#pragma unroll
        for (int i = 0; i < 8; ++i) lg[i] = la[(size_t)(m0 + t) * 8 + i];
        int e0 = 0; float b0 = lg[0];
#pragma unroll
        for (int i = 1; i < 8; ++i) if (lg[i] > b0) { b0 = lg[i]; e0 = i; }
        int e1 = -1; float b1 = -1e30f;
#pragma unroll
        for (int i = 0; i < 8; ++i) if (i != e0 && lg[i] > b1) { b1 = lg[i]; e1 = i; }
        float w1 = __expf(b1 - b0), s = 1.f + w1;
        sW0[t] = 1.f / s; sW1[t] = w1 / s; sE0[t] = e0; sE1[t] = e1;

#pragma unroll
        for (int i = 0; i < 8; ++i) lg[i] = lb[(size_t)(m0 + t) * 8 + i];
        int f0 = 0; float c0 = lg[0];
#pragma unroll
        for (int i = 1; i < 8; ++i) if (lg[i] > c0) { c0 = lg[i]; f0 = i; }
        int f1 = -1; float c1 = -1e30f;
#pragma unroll
        for (int i = 0; i < 8; ++i) if (i != f0 && lg[i] > c1) { c1 = lg[i]; f1 = i; }
        float wb1 = __expf(c1 - c0), sb = 1.f + wb1;
        float wb0s = 2.f / sb, wb1s = 2.f * wb1 / sb;   // SCALING=2 folded in
#pragma unroll
        for (int e = 0; e < 8; ++e)
            sCb[t][e] = (e == f0) ? wb0s : (e == f1) ? wb1s : 0.f;
    }
    __syncthreads();

    if (tx < 256) {
        const int t = tx >> 4, gg = tx & 15;
        const float w0 = sW0[t], w1 = sW1[t];
        const int e0 = sE0[t], e1 = sE1[t];
        const float cb = sCb[t][gg >> 1];
        h4 o;
#pragma unroll
        for (int j = 0; j < 4; ++j) {
            int r = (gg * 4 + j) & 7;
            float mid = w0 * (pL[0][t][e0 * 8 + r] + pL[1][t][e0 * 8 + r])
                      + w1 * (pL[0][t][e1 * 8 + r] + pL[1][t][e1 * 8 + r]);
            o[j] = (_Float16)(cb * mid);
        }
        *(h4*)(MbL + ((gg >> 1) * 16 + t) * 8 + (gg & 1) * 4) = o;
    }
    __syncthreads();

    // ================= phase 3: out[16x4096] = Mb[16x64] @ WbF ===============
    // A-frags in regs (loaded once); B-frags per-wave direct from L2-resident
    // fragment-ordered WbB; stores straight to out. Barrier-free, depth-1 pipe.
    // 8 waves each cover a 32-col slice per 256-col chunk, 16 chunks.
    h8 a30, a31;
    a30 = *(const h8*)(MbL + ((0 * 4 + kf) * 16 + mr) * 8);
    a31 = *(const h8*)(MbL + ((1 * 4 + kf) * 16 + mr) * 8);
    const uint4* wb4 = (const uint4*)WbB;
    const size_t bofs0 = (size_t)((0 * 4 + kf) * 4096);
    const size_t bofs1 = (size_t)((1 * 4 + kf) * 4096);
    float* outp = out + (size_t)(m0 + kf * 4) * D_OUT;

    uint4 C0[4], C1[4];
#define LDB3(Cd, CH) do { int n0_ = (CH) * 256 + w * 32 + mr;                  \
    Cd[0] = wb4[bofs0 + n0_];      Cd[1] = wb4[bofs0 + n0_ + 16];              \
    Cd[2] = wb4[bofs1 + n0_];      Cd[3] = wb4[bofs1 + n0_ + 16];              \
  } while (0)

#define CMP3(Cs, CH) do {                                                      \
    f4v o0 = (f4v){0.f,0.f,0.f,0.f}, o1 = (f4v){0.f,0.f,0.f,0.f};              \
    o0 = __builtin_amdgcn_mfma_f32_16x16x32_f16(a30, as_h8(Cs[0]), o0, 0,0,0); \
    o0 = __builtin_amdgcn_mfma_f32_16x16x32_f16(a31, as_h8(Cs[2]), o0, 0,0,0); \
    o1 = __builtin_amdgcn_mfma_f32_16x16x32_f16(a30, as_h8(Cs[1]), o1, 0,0,0); \
    o1 = __builtin_amdgcn_mfma_f32_16x16x32_f16(a31, as_h8(Cs[3]), o1, 0,0,0); \
    int n0_ = (CH) * 256 + w * 32 + mr;                                        \
    _Pragma("unroll") for (int r_ = 0; r_ < 4; ++r_) {                         \
        outp[(size_t)r_ * D_OUT + n0_]      = o0[r_];                          \
        outp[(size_t)r_ * D_OUT + n0_ + 16] = o1[r_]; }                        \
  } while (0)

    LDB3(C0, 0);
#pragma unroll 1
    for (int c = 0; c < 14; c += 2) {
        LDB3(C1, c + 1); CMP3(C0, c);
        LDB3(C0, c + 2); CMP3(C1, c + 1);
    }
    LDB3(C1, 15); CMP3(C0, 14); CMP3(C1, 15);
#undef LDB3
#undef CMP3

    // ================= aux_final (block 0 only) ==============================
    if (blockIdx.x == 0) {
        if (tx < 16) {
            double s = 0.0;
#pragma unroll
            for (int b = 0; b < 32; ++b) s += pax[b * 16 + tx];
            sl[tx] = s;
        }
        __syncthreads();
        if (tx == 0) {
            double pa[8], pb[8], ma = 0.0, mb = 0.0;
            for (int e = 0; e < 8; ++e) { pa[e] = sl[e] / 8192.0;     ma += pa[e] / 8.0; }
            for (int e = 0; e < 8; ++e) { pb[e] = sl[8 + e] / 8192.0; mb += pb[e] / 8.0; }
            double va = 0.0, vb = 0.0;
            for (int e = 0; e < 8; ++e) { double d = pa[e] - ma; va += d * d; }
            for (int e = 0; e < 8; ++e) { double d = pb[e] - mb; vb += d * d; }
            out[(size_t)T_TOK * D_OUT + 0] = (float)(8.0 * va / 7.0);
            out[(size_t)T_TOK * D_OUT + 1] = (float)(8.0 * vb / 7.0);
        }
    }
}

extern "C" void kernel_launch(void* const* d_in, const int* in_sizes, int n_in,
                              void* d_out, int out_size, void* d_ws, size_t ws_size,
                              hipStream_t stream) {
    const float* x  = (const float*)d_in[0];
    const float* la = (const float*)d_in[1];
    const float* lb = (const float*)d_in[2];
    const float* Wa = (const float*)d_in[3];
    const float* Wb = (const float*)d_in[4];
    float* out = (float*)d_out;

    char* ws = (char*)d_ws;
    _Float16* WaB = (_Float16*)ws;                 // 512 KB
    _Float16* WbB = (_Float16*)(ws + 524288);      // 512 KB
    double*   pax = (double*)(ws + 1048576);       // 4 KB

    prep<<<416, 256, 0, stream>>>(Wa, Wb, la, lb, WaB, WbB, pax);
    fused<<<512, 512, 0, stream>>>(x, WaB, WbB, la, lb, out, pax);
}

// Round 3
// 269.264 us; speedup vs baseline: 1.0626x; 1.0559x over previous
//
#include <hip/hip_runtime.h>

#define T_TOK 8192
#define D_IN  4096
#define D_OUT 4096

typedef _Float16 h2 __attribute__((ext_vector_type(2)));
typedef _Float16 h4 __attribute__((ext_vector_type(4)));
typedef _Float16 h8 __attribute__((ext_vector_type(8)));
typedef float    f4v __attribute__((ext_vector_type(4)));

__device__ __forceinline__ h2 pkrtz(float a, float b) {
    auto r = __builtin_amdgcn_cvt_pkrtz(a, b);
    h2 o; __builtin_memcpy(&o, &r, 4); return o;
}
__device__ __forceinline__ h8 cvt8(float4 f0, float4 f1) {
    h2 p0 = pkrtz(f0.x, f0.y), p1 = pkrtz(f0.z, f0.w);
    h2 p2 = pkrtz(f1.x, f1.y), p3 = pkrtz(f1.z, f1.w);
    return (h8){p0.x, p0.y, p1.x, p1.y, p2.x, p2.y, p3.x, p3.y};
}

// async 16B global->LDS (hardware DMA, no VGPR round-trip, m97/m193 mechanism)
__device__ __forceinline__ void gl_lds16(const void* g, void* l) {
    __builtin_amdgcn_global_load_lds(
        (const __attribute__((address_space(1))) unsigned int*)g,
        (__attribute__((address_space(3))) unsigned int*)l, 16, 0, 0);
}

// MFMA 16x16x32 f16 layouts (verified m89/m91/m120):
//   A-frag: lane holds A[m=lane&15][k=(lane>>4)*8+j], j=0..7 (one 16B h8)
//   B-frag: lane holds B[k=(lane>>4)*8+j][n=lane&15]
//   C/D:    row=(lane>>4)*4+reg, col=lane&15
// Fragment-chunk layout for a KxN panel: off = ((k>>3)*N + n)*8 + (k&7)

// ---- prep: Wa->WaB frags (bid<256), Wb->WbB frags (bid<384), aux_partial ----
__global__ __launch_bounds__(256)
void prep(const float* __restrict__ Wa, const float* __restrict__ Wb,
          const float* __restrict__ la, const float* __restrict__ lb,
          _Float16* __restrict__ WaB, _Float16* __restrict__ WbB,
          double* __restrict__ pax) {
    const int bid = blockIdx.x, tx = threadIdx.x;
    __shared__ double red[4][16];
    if (bid < 256) {
        // Wa [er=64][k=4096] f32 -> frag order ((k>>3)*64+er)*8+(k&7)
        int gid = bid * 256 + tx;                // 0..65535
        int er = gid >> 10, k0 = (gid & 1023) * 4;
        float4 v = ((const float4*)Wa)[gid];
        h2 p0 = pkrtz(v.x, v.y), p1 = pkrtz(v.z, v.w);
        h4 o = { p0.x, p0.y, p1.x, p1.y };
        *(h4*)(WaB + ((k0 >> 3) * 64 + er) * 8 + (k0 & 7)) = o;
    } else if (bid < 384) {
        // Wb [e][o][r] f32 -> frag order ((er>>3)*4096+o)*8+(er&7), er=e*8+r
        int gid = (bid - 256) * 256 + tx;        // 0..32767
        int e = gid >> 12, o = gid & 4095;
        const float4* p = (const float4*)(Wb + ((size_t)e * 4096 + o) * 8);
        h8 v = cvt8(p[0], p[1]);
        *(h8*)(WbB + ((size_t)e * 4096 + o) * 8) = v;
    } else {
        // aux_partial: 32 blocks, per-token full softmax partial sums (f64)
        const int ab = bid - 384;
        const int t = ab * 256 + tx;
        double loc[16];
        {
            float l[8];
#pragma unroll
            for (int i = 0; i < 8; ++i) l[i] = la[(size_t)t * 8 + i];
            float m = l[0];
#pragma unroll
            for (int i = 1; i < 8; ++i) m = fmaxf(m, l[i]);
            float s = 0.f, e[8];
#pragma unroll
            for (int i = 0; i < 8; ++i) { e[i] = __expf(l[i] - m); s += e[i]; }
#pragma unroll
            for (int i = 0; i < 8; ++i) loc[i] = (double)(e[i] / s);
        }
        {
            float l[8];
#pragma unroll
            for (int i = 0; i < 8; ++i) l[i] = lb[(size_t)t * 8 + i];
            float m = l[0];
#pragma unroll
            for (int i = 1; i < 8; ++i) m = fmaxf(m, l[i]);
            float s = 0.f, e[8];
#pragma unroll
            for (int i = 0; i < 8; ++i) { e[i] = __expf(l[i] - m); s += e[i]; }
#pragma unroll
            for (int i = 0; i < 8; ++i) loc[8 + i] = (double)(e[i] / s);
        }
        const int lane = tx & 63, wid = tx >> 6;
#pragma unroll
        for (int v = 0; v < 16; ++v) {
            double s = loc[v];
#pragma unroll
            for (int off = 32; off > 0; off >>= 1) s += __shfl_down(s, off, 64);
            if (lane == 0) red[wid][v] = s;
        }
        __syncthreads();
        if (tx < 16)
            pax[ab * 16 + tx] = red[0][tx] + red[1][tx] + red[2][tx] + red[3][tx];
    }
}

// ---- fused: GEMM1 (x@WaT) + routing + GEMM2 (Mb@WbF) in one pass ------------
// 512 blocks x 256 thr (4 waves); 16 tokens/block; 2 blocks/CU.
// Both GEMM phases: global_load_lds double-buffered LDS staging, 1 barrier/iter.
__global__ __launch_bounds__(256)
void fused(const float* __restrict__ x, const _Float16* __restrict__ WaB,
           const _Float16* __restrict__ WbB, const float* __restrict__ la,
           const float* __restrict__ lb, float* __restrict__ out,
           const double* __restrict__ pax) {
    __shared__ union {
        struct { float xb[2][2048]; _Float16 wab[2][8192]; } p1;  // 16KB + 32KB
        struct { _Float16 wbb[2][8192]; } p3;                     // 32KB (overlay)
    } U;
    __shared__ float    pL[16][66];      // part[t][er], padded
    __shared__ _Float16 MbL[1024];       // Mb frags: ((er>>3)*16+t)*8+(er&7)
    __shared__ float    sW0[16], sW1[16], sCb[16][8];
    __shared__ int      sE0[16], sE1[16];
    __shared__ double   sl[16];

    const int tx = threadIdx.x, l = tx & 63, w = tx >> 6;
    const int mr = l & 15, kf = l >> 4;
    const int m0 = blockIdx.x * 16;
    const int er1 = w * 16 + mr;         // wave's er-frag column (phase 1)

    // ================= phase 1: part[16x64] = x[16x4096] @ WaT ===============
    // Stage per 128-K chunk: x 8KB f32 (XOR-swizzled source -> linear LDS dest,
    // rule #21) + WaB 16KB (contiguous frag chunk). 1 barrier/iter, dbuf.
    f4v acc = (f4v){0.f, 0.f, 0.f, 0.f};

#define STAGE1(IT, BUF) do {                                                   \
    _Pragma("unroll") for (int i_ = 0; i_ < 2; ++i_) {                         \
        int j_ = w * 2 + i_;                                                   \
        int row_ = j_ * 2 + (l >> 5);                                          \
        int cb_ = ((l & 31) * 16) ^ ((row_ & 7) << 4);                         \
        const char* src_ = (const char*)x                                      \
            + (((size_t)(m0 + row_) * D_IN + (size_t)(IT) * 128) << 2) + cb_;  \
        gl_lds16(src_, (char*)U.p1.xb[BUF] + j_ * 1024);                       \
    }                                                                          \
    _Pragma("unroll") for (int i_ = 0; i_ < 4; ++i_) {                         \
        int j_ = w * 4 + i_;                                                   \
        const char* src_ = (const char*)WaB + (size_t)(IT) * 16384             \
            + j_ * 1024 + l * 16;                                              \
        gl_lds16(src_, (char*)U.p1.wab[BUF] + j_ * 1024);                      \
    }                                                                          \
  } while (0)

#define CMP1(BUF) do {                                                         \
    const char* xb_ = (const char*)U.p1.xb[BUF] + mr * 512;                    \
    const int sw_ = (mr & 7) << 4;                                             \
    _Pragma("unroll") for (int ks_ = 0; ks_ < 4; ++ks_) {                      \
        int c0_ = ks_ * 128 + kf * 32;                                         \
        float4 f0_ = *(const float4*)(xb_ + ((c0_) ^ sw_));                    \
        float4 f1_ = *(const float4*)(xb_ + ((c0_ + 16) ^ sw_));               \
        h8 a_ = cvt8(f0_, f1_);                                                \
        h8 b_ = *(const h8*)((const char*)U.p1.wab[BUF]                        \
                             + ((ks_ * 4 + kf) * 64 + er1) * 16);              \
        acc = __builtin_amdgcn_mfma_f32_16x16x32_f16(a_, b_, acc, 0, 0, 0);    \
    }                                                                          \
  } while (0)

    STAGE1(0, 0);
    __syncthreads();
#pragma unroll 1
    for (int it = 0; it < 32; ++it) {
        if (it < 31) STAGE1(it + 1, (it & 1) ^ 1);
        CMP1(it & 1);
        __syncthreads();
    }
#undef STAGE1
#undef CMP1

    // ================= phase 2: routing -> Mb fragment panel =================
#pragma unroll
    for (int r = 0; r < 4; ++r) pL[kf * 4 + r][er1] = acc[r];
    __syncthreads();

    if (tx < 16) {
        const int t = tx;
        float lg[8];
#pragma unroll
        for (int i = 0; i < 8; ++i) lg[i] = la[(size_t)(m0 + t) * 8 + i];
        int e0 = 0; float b0 = lg[0];
#pragma unroll
        for (int i = 1; i < 8; ++i) if (lg[i] > b0) { b0 = lg[i]; e0 = i; }
        int e1 = -1; float b1 = -1e30f;
#pragma unroll
        for (int i = 0; i < 8; ++i) if (i != e0 && lg[i] > b1) { b1 = lg[i]; e1 = i; }
        float w1 = __expf(b1 - b0), s = 1.f + w1;
        sW0[t] = 1.f / s; sW1[t] = w1 / s; sE0[t] = e0; sE1[t] = e1;

#pragma unroll
        for (int i = 0; i < 8; ++i) lg[i] = lb[(size_t)(m0 + t) * 8 + i];
        int f0 = 0; float c0 = lg[0];
#pragma unroll
        for (int i = 1; i < 8; ++i) if (lg[i] > c0) { c0 = lg[i]; f0 = i; }
        int f1 = -1; float c1 = -1e30f;
#pragma unroll
        for (int i = 0; i < 8; ++i) if (i != f0 && lg[i] > c1) { c1 = lg[i]; f1 = i; }
        float wb1 = __expf(c1 - c0), sb = 1.f + wb1;
        float wb0s = 2.f / sb, wb1s = 2.f * wb1 / sb;   // SCALING=2 folded in
#pragma unroll
        for (int e = 0; e < 8; ++e)
            sCb[t][e] = (e == f0) ? wb0s : (e == f1) ? wb1s : 0.f;
    }
    __syncthreads();

    {
        const int t = tx >> 4, gg = tx & 15;
        const float w0 = sW0[t], w1 = sW1[t];
        const int e0 = sE0[t], e1 = sE1[t];
        const float cb = sCb[t][gg >> 1];
        h4 o;
#pragma unroll
        for (int j = 0; j < 4; ++j) {
            int r = (gg * 4 + j) & 7;
            float mid = w0 * pL[t][e0 * 8 + r] + w1 * pL[t][e1 * 8 + r];
            o[j] = (_Float16)(cb * mid);
        }
        *(h4*)(MbL + ((gg >> 1) * 16 + t) * 8 + (gg & 1) * 4) = o;
    }
    __syncthreads();

    // ================= phase 3: out[16x4096] = Mb[16x64] @ WbF ===============
    // A-frags in regs; WbB staged per 128-col chunk (16KB dbuf, conflict-free
    // frag reads); stores straight to out. 1 barrier/iter.
    h8 a30 = *(const h8*)(MbL + ((0 * 4 + kf) * 16 + mr) * 8);
    h8 a31 = *(const h8*)(MbL + ((1 * 4 + kf) * 16 + mr) * 8);
    float* outp = out + (size_t)(m0 + kf * 4) * D_OUT;

#define STAGE3(CH, BUF) do {                                                   \
    _Pragma("unroll") for (int i_ = 0; i_ < 4; ++i_) {                         \
        int j_ = w * 4 + i_;                                                   \
        const char* src_ = (const char*)WbB + (size_t)(j_ >> 1) * 65536        \
            + (size_t)(CH) * 2048 + (j_ & 1) * 1024 + l * 16;                  \
        gl_lds16(src_, (char*)U.p3.wbb[BUF] + j_ * 1024);                      \
    }                                                                          \
  } while (0)

#define CMP3(BUF, CH) do {                                                     \
    f4v o0 = (f4v){0.f,0.f,0.f,0.f}, o1 = (f4v){0.f,0.f,0.f,0.f};              \
    _Pragma("unroll") for (int ks_ = 0; ks_ < 2; ++ks_) {                      \
        const char* bb_ = (const char*)U.p3.wbb[BUF]                           \
            + ((ks_ * 4 + kf) * 128 + w * 32 + mr) * 16;                       \
        h8 b0_ = *(const h8*)(bb_);                                            \
        h8 b1_ = *(const h8*)(bb_ + 256);                                      \
        h8 af_ = ks_ ? a31 : a30;                                              \
        o0 = __builtin_amdgcn_mfma_f32_16x16x32_f16(af_, b0_, o0, 0, 0, 0);    \
        o1 = __builtin_amdgcn_mfma_f32_16x16x32_f16(af_, b1_, o1, 0, 0, 0);    \
    }                                                                          \
    int n0_ = (CH) * 128 + w * 32 + mr;                                        \
    _Pragma("unroll") for (int r_ = 0; r_ < 4; ++r_) {                         \
        outp[(size_t)r_ * D_OUT + n0_]      = o0[r_];                          \
        outp[(size_t)r_ * D_OUT + n0_ + 16] = o1[r_]; }                        \
  } while (0)

    STAGE3(0, 0);
    __syncthreads();
#pragma unroll 1
    for (int c = 0; c < 32; ++c) {
        if (c < 31) STAGE3(c + 1, (c & 1) ^ 1);
        CMP3(c & 1, c);
        __syncthreads();
    }
#undef STAGE3
#undef CMP3

    // ================= aux_final (block 0 only) ==============================
    if (blockIdx.x == 0) {
        if (tx < 16) {
            double s = 0.0;
#pragma unroll
            for (int b = 0; b < 32; ++b) s += pax[b * 16 + tx];
            sl[tx] = s;
        }
        __syncthreads();
        if (tx == 0) {
            double pa[8], pb[8], ma = 0.0, mb = 0.0;
            for (int e = 0; e < 8; ++e) { pa[e] = sl[e] / 8192.0;     ma += pa[e] / 8.0; }
            for (int e = 0; e < 8; ++e) { pb[e] = sl[8 + e] / 8192.0; mb += pb[e] / 8.0; }
            double va = 0.0, vb = 0.0;
            for (int e = 0; e < 8; ++e) { double d = pa[e] - ma; va += d * d; }
            for (int e = 0; e < 8; ++e) { double d = pb[e] - mb; vb += d * d; }
            out[(size_t)T_TOK * D_OUT + 0] = (float)(8.0 * va / 7.0);
            out[(size_t)T_TOK * D_OUT + 1] = (float)(8.0 * vb / 7.0);
        }
    }
}

extern "C" void kernel_launch(void* const* d_in, const int* in_sizes, int n_in,
                              void* d_out, int out_size, void* d_ws, size_t ws_size,
                              hipStream_t stream) {
    const float* x  = (const float*)d_in[0];
    const float* la = (const float*)d_in[1];
    const float* lb = (const float*)d_in[2];
    const float* Wa = (const float*)d_in[3];
    const float* Wb = (const float*)d_in[4];
    float* out = (float*)d_out;

    char* ws = (char*)d_ws;
    _Float16* WaB = (_Float16*)ws;                 // 512 KB
    _Float16* WbB = (_Float16*)(ws + 524288);      // 512 KB
    double*   pax = (double*)(ws + 1048576);       // 4 KB

    prep<<<416, 256, 0, stream>>>(Wa, Wb, la, lb, WaB, WbB, pax);
    fused<<<512, 256, 0, stream>>>(x, WaB, WbB, la, lb, out, pax);
}